// Round 4
// baseline (762.802 us; speedup 1.0000x reference)
//
#include <hip/hip_runtime.h>
#include <math.h>

// Problem constants (B=8, L=4096, D=512, H=8, top_k = int(log(4096)) = 8)
#define NB 8
#define NL 4096
#define ND 512
#define NK 8

typedef unsigned short ushort_t;
typedef __bf16 bf16x8 __attribute__((ext_vector_type(8)));
typedef float f32x4 __attribute__((ext_vector_type(4)));

__device__ __forceinline__ unsigned short f2bf(float x) {
    unsigned u = __builtin_bit_cast(unsigned, x);
    u += 0x7fff + ((u >> 16) & 1);   // round-to-nearest-even
    return (unsigned short)(u >> 16);
}
__device__ __forceinline__ float bf2f(unsigned short b) {
    unsigned u = ((unsigned)b) << 16;
    return __builtin_bit_cast(float, u);
}

// ---------------------------------------------------------------------------
// Weight prep (one kernel): z=0: M = Wq^T Wk -> BsM split; z=1: Wov = Wo Wv -> BsW
// ---------------------------------------------------------------------------
__global__ void k_prep(const float* __restrict__ Wq, const float* __restrict__ Wk,
                       const float* __restrict__ Wo, const float* __restrict__ Wv,
                       ushort_t* __restrict__ BsM, ushort_t* __restrict__ BsW) {
    int i = blockIdx.y * 16 + threadIdx.y;
    int j = blockIdx.x * 16 + threadIdx.x;
    float acc = 0.f;
    if (blockIdx.z == 0) {
        for (int k = 0; k < ND; ++k) acc += Wq[k * ND + i] * Wk[k * ND + j];
    } else {
        for (int k = 0; k < ND; ++k) acc += Wo[i * ND + k] * Wv[k * ND + j];
    }
    ushort_t hi = f2bf(acc);
    ushort_t lo = f2bf(acc - bf2f(hi));
    ushort_t* dst = (blockIdx.z == 0) ? BsM : BsW;
    dst[(size_t)i * 1024 + j] = hi;
    dst[(size_t)i * 1024 + 512 + j] = lo;
}

// bp[i] = bo[i] + sum_k Wo[i,k]*bv[k]
__global__ void k_biasprep(const float* __restrict__ Wo, const float* __restrict__ bv,
                           const float* __restrict__ bo, float* __restrict__ bp) {
    int i = blockIdx.x * blockDim.x + threadIdx.x;
    float acc = bo[i];
    for (int k = 0; k < ND; ++k) acc += Wo[i * ND + k] * bv[k];
    bp[i] = acc;
}

// Split fp32 rows into [row][0:512]=hi bf16, [row][512:1024]=lo bf16.
__global__ __launch_bounds__(256) void k_split(const float* __restrict__ src,
                                               ushort_t* __restrict__ dst) {
    int gid = blockIdx.x * 256 + threadIdx.x;
    int row = gid >> 7;
    int kc = (gid & 127) * 4;
    float4 v = *(const float4*)(src + (size_t)row * ND + kc);
    ushort4 hi, lo;
    hi.x = f2bf(v.x); lo.x = f2bf(v.x - bf2f(hi.x));
    hi.y = f2bf(v.y); lo.y = f2bf(v.y - bf2f(hi.y));
    hi.z = f2bf(v.z); lo.z = f2bf(v.z - bf2f(hi.z));
    hi.w = f2bf(v.w); lo.w = f2bf(v.w - bf2f(hi.w));
    *(ushort4*)(dst + (size_t)row * 1024 + kc) = hi;
    *(ushort4*)(dst + (size_t)row * 1024 + 512 + kc) = lo;
}

// ---------------------------------------------------------------------------
// Split-bf16 MFMA GEMM:  C[r,n] = sum_k A[r,k] * Brow[n,k]
// A, B pre-split bf16 [rows][1024] = hi(512)|lo(512); staged via global_load_lds
// width=16 with XOR chunk swizzle (c' = c ^ ((row>>1)&3)).
// TERMS=3: Ah*Bh + Ah*Bl + Al*Bh (split precision). TERMS=1: Ah*Bh (plain bf16).
// 128x128 C-tile, 256 thr = 4 waves (2x2), 4x4 16x16x32 MFMA frags per wave.
// EPI=0: write transposed YT[b,n,l]; EPI=1: bias + plain [r,n].
// grid = dim3(4, 256): x = N-tile (L2/L3 temporal reuse of A), y = row-tile.
// ---------------------------------------------------------------------------
template <int TERMS, int EPI>
__global__ __launch_bounds__(256) void k_gemm(const ushort_t* __restrict__ As,
                                              const ushort_t* __restrict__ Bs,
                                              const float* __restrict__ bp,
                                              float* __restrict__ Out) {
    constexpr int NTILE = (TERMS == 3) ? 4 : 2;
    __shared__ union USm {
        ushort_t tiles[NTILE * 4096];   // [ahi | (alo) | bhi | (blo)], 8 KB each
        float t[32 * 132];              // epilogue transpose (EPI=0, TERMS=3)
    } sm;
    ushort_t* ahi = sm.tiles;
    ushort_t* alo = sm.tiles + 4096;
    ushort_t* bhi = sm.tiles + ((TERMS == 3) ? 8192 : 4096);
    ushort_t* blo = sm.tiles + 12288;

    const int tid = threadIdx.x;
    const int n0 = blockIdx.x * 128;
    const int l0 = blockIdx.y * 128;
    const int lane = tid & 63;
    const int w = tid >> 6;
    const int wr = (w & 1) * 64;
    const int wc = (w >> 1) * 64;
    const int m = lane & 15;
    const int quad = lane >> 4;

    f32x4 acc[4][4];
#pragma unroll
    for (int i = 0; i < 4; ++i)
#pragma unroll
        for (int j = 0; j < 4; ++j) acc[i][j] = (f32x4){0.f, 0.f, 0.f, 0.f};

    for (int k0 = 0; k0 < ND; k0 += 32) {
        __syncthreads();   // prior iteration's fragment reads complete
#pragma unroll
        for (int v = 0; v < 2; ++v) {
            int q = v * 256 + tid;            // 16B chunk id within 128x32 tile
            int r = q >> 2;                   // tile row
            int c = (q & 3) ^ ((r >> 1) & 3); // swizzled source chunk
            const ushort_t* asrc = As + (size_t)(l0 + r) * 1024 + k0 + c * 8;
            __builtin_amdgcn_global_load_lds(
                (const __attribute__((address_space(1))) unsigned int*)asrc,
                (__attribute__((address_space(3))) unsigned int*)&ahi[q * 8], 16, 0, 0);
            const ushort_t* bsrc = Bs + (size_t)(n0 + r) * 1024 + k0 + c * 8;
            __builtin_amdgcn_global_load_lds(
                (const __attribute__((address_space(1))) unsigned int*)bsrc,
                (__attribute__((address_space(3))) unsigned int*)&bhi[q * 8], 16, 0, 0);
            if (TERMS == 3) {
                __builtin_amdgcn_global_load_lds(
                    (const __attribute__((address_space(1))) unsigned int*)(asrc + 512),
                    (__attribute__((address_space(3))) unsigned int*)&alo[q * 8], 16, 0, 0);
                __builtin_amdgcn_global_load_lds(
                    (const __attribute__((address_space(1))) unsigned int*)(bsrc + 512),
                    (__attribute__((address_space(3))) unsigned int*)&blo[q * 8], 16, 0, 0);
            }
        }
        __syncthreads();   // waits vmcnt(0): DMA landed

        bf16x8 ah[4], al[4];
#pragma unroll
        for (int i = 0; i < 4; ++i) {
            int row = wr + 16 * i + m;
            int off = row * 32 + ((quad ^ ((row >> 1) & 3)) * 8);
            ah[i] = *(const bf16x8*)&ahi[off];
            if (TERMS == 3) al[i] = *(const bf16x8*)&alo[off];
        }
#pragma unroll
        for (int j = 0; j < 4; ++j) {
            int row = wc + 16 * j + m;
            int off = row * 32 + ((quad ^ ((row >> 1) & 3)) * 8);
            bf16x8 bh = *(const bf16x8*)&bhi[off];
#pragma unroll
            for (int i = 0; i < 4; ++i)
                acc[i][j] = __builtin_amdgcn_mfma_f32_16x16x32_bf16(ah[i], bh, acc[i][j], 0, 0, 0);
            if (TERMS == 3) {
                bf16x8 bl = *(const bf16x8*)&blo[off];
#pragma unroll
                for (int i = 0; i < 4; ++i) {
                    acc[i][j] = __builtin_amdgcn_mfma_f32_16x16x32_bf16(ah[i], bl, acc[i][j], 0, 0, 0);
                    acc[i][j] = __builtin_amdgcn_mfma_f32_16x16x32_bf16(al[i], bh, acc[i][j], 0, 0, 0);
                }
            }
        }
    }

    if (EPI == 1) {
        // bias + plain [row, col]
#pragma unroll
        for (int j = 0; j < 4; ++j) {
            int col = n0 + wc + 16 * j + m;
            float bv = bp[col];
#pragma unroll
            for (int i = 0; i < 4; ++i) {
                size_t rbase = (size_t)(l0 + wr + 16 * i + quad * 4) * ND + col;
#pragma unroll
                for (int r = 0; r < 4; ++r)
                    Out[rbase + (size_t)r * ND] = acc[i][j][r] + bv;
            }
        }
    } else {
        // transposed write YT[b, n, l] via LDS, 32-col chunks
#pragma unroll
        for (int c = 0; c < 4; ++c) {
            __syncthreads();
            if ((wc >> 6) == (c >> 1)) {
                int jb = (c & 1) * 2;
#pragma unroll
                for (int jj = 0; jj < 2; ++jj) {
                    int j = jb + jj;
                    int cl = 16 * jj + m;
#pragma unroll
                    for (int i = 0; i < 4; ++i)
#pragma unroll
                        for (int r = 0; r < 4; ++r)
                            sm.t[cl * 132 + wr + 16 * i + quad * 4 + r] = acc[i][j][r];
                }
            }
            __syncthreads();
#pragma unroll
            for (int it = 0; it < 16; ++it) {
                int idx = it * 256 + tid;
                int cl = idx >> 7;
                int row = idx & 127;
                int rg = l0 + row;
                Out[((size_t)((rg >> 12) * ND + n0 + c * 32 + cl)) * NL + (rg & 4095)] =
                    sm.t[cl * 132 + row];
            }
        }
    }
}

// ---------------------------------------------------------------------------
// 16-point in-register DFT (natural in/out). DIR=+1 fwd (e^{-i}), -1 inverse.
// ---------------------------------------------------------------------------
template <int DIR>
__device__ __forceinline__ void fft16(float2* v) {
    const float ct[8] = {1.f, 0.923879533f, 0.707106781f, 0.382683432f,
                         0.f, -0.382683432f, -0.707106781f, -0.923879533f};
    const float st[8] = {0.f, 0.382683432f, 0.707106781f, 0.923879533f,
                         1.f, 0.923879533f, 0.707106781f, 0.382683432f};
    const int br[16] = {0, 8, 4, 12, 2, 10, 6, 14, 1, 9, 5, 13, 3, 11, 7, 15};
    float2 a[16];
#pragma unroll
    for (int i = 0; i < 16; ++i) a[i] = v[br[i]];
#pragma unroll
    for (int s = 1; s <= 4; ++s) {
        const int L = 1 << s, h = L >> 1;
#pragma unroll
        for (int g = 0; g < 16; g += L)
#pragma unroll
            for (int p = 0; p < h; ++p) {
                int k = p << (4 - s);
                float wr = ct[k];
                float wi = (DIR > 0) ? -st[k] : st[k];
                int i1 = g + p, i2 = i1 + h;
                float tr = wr * a[i2].x - wi * a[i2].y;
                float ti = wr * a[i2].y + wi * a[i2].x;
                a[i2].x = a[i1].x - tr; a[i2].y = a[i1].y - ti;
                a[i1].x += tr;          a[i1].y += ti;
            }
    }
#pragma unroll
    for (int i = 0; i < 16; ++i) v[i] = a[i];
}

__device__ __forceinline__ float2 cmul(float2 a, float2 b) {
    return make_float2(a.x * b.x - a.y * b.y, a.x * b.y + a.y * b.x);
}
#define PADI(i) ((i) + ((i) >> 4))

// ---------------------------------------------------------------------------
// Forward: per (batch, group of 8 channels): z = x + i*y, 4096-pt Stockham
// radix-16 (3 stages). x read directly from X[b, l, c] (column access; 8
// consecutive channels share a 32B chunk -> L2/L3 serves). y from YT (coalesced).
// Accumulate X_c(f)*conj(Y_c(f)) = Im(Z_f*Z_{-f})/2 + i*(|Z_f|^2-|Z_{-f}|^2)/4.
// ---------------------------------------------------------------------------
__global__ __launch_bounds__(256) void k_fft_fwd(const float* __restrict__ X,
                                                 const float* __restrict__ YT,
                                                 float2* __restrict__ partial) {
    __shared__ float2 data[4352];   // 4096 + pad
    const int t = threadIdx.x;
    const int b = blockIdx.x >> 6;
    const int g = blockIdx.x & 63;

    float sv, cv;
    sincosf(-6.283185307179586f * (float)(t & 15) / 256.0f, &sv, &cv);
    const float2 w2 = make_float2(cv, sv);
    sincosf(-6.283185307179586f * (float)t / 4096.0f, &sv, &cv);
    const float2 w3 = make_float2(cv, sv);

    float2 acc[16];
#pragma unroll
    for (int r = 0; r < 16; ++r) acc[r] = make_float2(0.f, 0.f);

    for (int ch = 0; ch < 8; ++ch) {
        int c = g * 8 + ch;
        const float* xb = X + (size_t)b * NL * ND + c;     // stride ND per l
        const float* yr = YT + ((size_t)b * ND + c) * NL;  // contiguous in l
        float2 v[16];
        // stage 1 (Ns=1): read natural, fft16, write idx 16t+m
#pragma unroll
        for (int mm = 0; mm < 16; ++mm)
            v[mm] = make_float2(xb[(size_t)(t + 256 * mm) * ND], yr[t + 256 * mm]);
        fft16<1>(v);
        __syncthreads();   // prior channel's pair-reads done
#pragma unroll
        for (int mm = 0; mm < 16; ++mm) data[PADI(16 * t + mm)] = v[mm];
        __syncthreads();
        // stage 2 (Ns=16)
#pragma unroll
        for (int mm = 0; mm < 16; ++mm) v[mm] = data[PADI(t + 256 * mm)];
        {
            float2 wm = make_float2(1.f, 0.f);
#pragma unroll
            for (int mm = 1; mm < 16; ++mm) { wm = cmul(wm, w2); v[mm] = cmul(v[mm], wm); }
        }
        fft16<1>(v);
        __syncthreads();
        {
            int base = (t >> 4) * 256 + (t & 15);
#pragma unroll
            for (int mm = 0; mm < 16; ++mm) data[PADI(base + 16 * mm)] = v[mm];
        }
        __syncthreads();
        // stage 3 (Ns=256) -> natural-order Z in registers
#pragma unroll
        for (int mm = 0; mm < 16; ++mm) v[mm] = data[PADI(t + 256 * mm)];
        {
            float2 wm = make_float2(1.f, 0.f);
#pragma unroll
            for (int mm = 1; mm < 16; ++mm) { wm = cmul(wm, w3); v[mm] = cmul(v[mm], wm); }
        }
        fft16<1>(v);
        __syncthreads();
#pragma unroll
        for (int mm = 0; mm < 16; ++mm) data[PADI(t + 256 * mm)] = v[mm];
        __syncthreads();
        // cross-spectrum accumulate
#pragma unroll
        for (int mm = 0; mm < 16; ++mm) {
            int f = t + 256 * mm;
            float2 A = v[mm];
            float2 Bz = data[PADI((4096 - f) & 4095)];
            acc[mm].x += 0.5f * (A.x * Bz.y + A.y * Bz.x);
            acc[mm].y += 0.25f * ((A.x * A.x + A.y * A.y) - (Bz.x * Bz.x + Bz.y * Bz.y));
        }
    }
    float2* out = partial + ((size_t)b * 64 + g) * 4096;
#pragma unroll
    for (int mm = 0; mm < 16; ++mm) out[256 * mm + t] = acc[mm];
}

// Reduce 64 partials -> Cf[b][f]
__global__ __launch_bounds__(256) void k_reduce(const float2* __restrict__ partial,
                                                float2* __restrict__ Cf) {
    int b = blockIdx.x >> 4;
    int f = (blockIdx.x & 15) * 256 + threadIdx.x;
    float2 s = make_float2(0.f, 0.f);
    for (int g = 0; g < 64; ++g) {
        float2 v = partial[((size_t)(b * 64 + g)) * 4096 + f];
        s.x += v.x; s.y += v.y;
    }
    Cf[(size_t)b * 4096 + f] = s;
}

// ---------------------------------------------------------------------------
// Fused inverse 4096-pt Stockham + top-8 + softmax (8 blocks).
// ---------------------------------------------------------------------------
__global__ __launch_bounds__(256) void k_ifft_topk(const float2* __restrict__ Cf,
                                                   float* __restrict__ wts,
                                                   int* __restrict__ dly) {
    __shared__ union {
        float2 data[4352];
        struct { float vals[4096]; float rv[256]; int ri[256];
                 float tv[NK]; int tix[NK]; } tk;
    } sm;
    const int t = threadIdx.x;
    const int b = blockIdx.x;
    float sv, cv;
    sincosf(6.283185307179586f * (float)(t & 15) / 256.0f, &sv, &cv);
    const float2 w2 = make_float2(cv, sv);
    sincosf(6.283185307179586f * (float)t / 4096.0f, &sv, &cv);
    const float2 w3 = make_float2(cv, sv);

    float2 v[16];
#pragma unroll
    for (int mm = 0; mm < 16; ++mm) v[mm] = Cf[(size_t)b * 4096 + t + 256 * mm];
    fft16<-1>(v);
#pragma unroll
    for (int mm = 0; mm < 16; ++mm) sm.data[PADI(16 * t + mm)] = v[mm];
    __syncthreads();
#pragma unroll
    for (int mm = 0; mm < 16; ++mm) v[mm] = sm.data[PADI(t + 256 * mm)];
    {
        float2 wm = make_float2(1.f, 0.f);
#pragma unroll
        for (int mm = 1; mm < 16; ++mm) { wm = cmul(wm, w2); v[mm] = cmul(v[mm], wm); }
    }
    fft16<-1>(v);
    __syncthreads();
    {
        int base = (t >> 4) * 256 + (t & 15);
#pragma unroll
        for (int mm = 0; mm < 16; ++mm) sm.data[PADI(base + 16 * mm)] = v[mm];
    }
    __syncthreads();
#pragma unroll
    for (int mm = 0; mm < 16; ++mm) v[mm] = sm.data[PADI(t + 256 * mm)];
    {
        float2 wm = make_float2(1.f, 0.f);
#pragma unroll
        for (int mm = 1; mm < 16; ++mm) { wm = cmul(wm, w3); v[mm] = cmul(v[mm], wm); }
    }
    fft16<-1>(v);
    __syncthreads();    // done with sm.data; switch to topk view
    const float scale = 1.0f / (4096.0f * 512.0f);
#pragma unroll
    for (int mm = 0; mm < 16; ++mm) sm.tk.vals[t + 256 * mm] = v[mm].x * scale;
    __syncthreads();

    for (int it = 0; it < NK; ++it) {
        float bv = -3.0e38f;
        int bi = 0;
        for (int q = t; q < 4096; q += 256) {
            float x = sm.tk.vals[q];
            if (x > bv) { bv = x; bi = q; }
        }
        sm.tk.rv[t] = bv;
        sm.tk.ri[t] = bi;
        __syncthreads();
        for (int off = 128; off > 0; off >>= 1) {
            if (t < off) {
                if (sm.tk.rv[t + off] > sm.tk.rv[t]) {
                    sm.tk.rv[t] = sm.tk.rv[t + off];
                    sm.tk.ri[t] = sm.tk.ri[t + off];
                }
            }
            __syncthreads();
        }
        if (t == 0) {
            sm.tk.tv[it] = sm.tk.rv[0];
            sm.tk.tix[it] = sm.tk.ri[0];
            sm.tk.vals[sm.tk.ri[0]] = -3.0e38f;
        }
        __syncthreads();
    }
    if (t == 0) {
        float mx = sm.tk.tv[0];
        float e[NK], s = 0.f;
        for (int i = 0; i < NK; ++i) { e[i] = expf(sm.tk.tv[i] - mx); s += e[i]; }
        for (int i = 0; i < NK; ++i) {
            wts[b * NK + i] = e[i] / s;
            dly[b * NK + i] = sm.tk.tix[i];
        }
    }
}

// ---------------------------------------------------------------------------
// Out[b,l,:] = sum_i w[b,i] * Z[b,(l+d_i)%L,:]   (Z = X@Wov^T + bp, fp32)
// ---------------------------------------------------------------------------
__global__ __launch_bounds__(256) void k_gather(const float* __restrict__ Z,
                                                const float* __restrict__ wts,
                                                const int* __restrict__ dly,
                                                float* __restrict__ Out) {
    __shared__ float sw[NK];
    __shared__ int sd[NK];
    int gid = blockIdx.x * 256 + threadIdx.x;
    int b = gid >> 19;
    int rem = gid & 524287;
    int l = rem >> 7;
    int c4 = rem & 127;
    if (threadIdx.x < NK) {
        sw[threadIdx.x] = wts[b * NK + threadIdx.x];
        sd[threadIdx.x] = dly[b * NK + threadIdx.x];
    }
    __syncthreads();
    const float4* Zb = (const float4*)Z + (size_t)b * 524288;
    float4 s = make_float4(0.f, 0.f, 0.f, 0.f);
#pragma unroll
    for (int i = 0; i < NK; ++i) {
        int ls = (l + sd[i]) & (NL - 1);
        float4 v = Zb[(size_t)ls * 128 + c4];
        float w = sw[i];
        s.x += w * v.x;
        s.y += w * v.y;
        s.z += w * v.z;
        s.w += w * v.w;
    }
    ((float4*)Out)[gid] = s;
}

// ---------------------------------------------------------------------------
extern "C" void kernel_launch(void* const* d_in, const int* in_sizes, int n_in,
                              void* d_out, int out_size, void* d_ws, size_t ws_size,
                              hipStream_t stream) {
    (void)in_sizes; (void)n_in; (void)out_size; (void)ws_size;
    const float* X  = (const float*)d_in[0];
    const float* Wq = (const float*)d_in[1];
    const float* Wk = (const float*)d_in[3];
    const float* Wv = (const float*)d_in[5];
    const float* bv = (const float*)d_in[6];
    const float* Wo = (const float*)d_in[7];
    const float* bo = (const float*)d_in[8];
    float* Out = (float*)d_out;

    char* ws = (char*)d_ws;
    const size_t MB = 1024 * 1024;
    // misc [0,5) MiB
    ushort_t* BsM = (ushort_t*)(ws + 0 * MB);            // 1 MB [512][1024] hi|lo
    ushort_t* BsW = (ushort_t*)(ws + 1 * MB);            // 1 MB
    float*    bp  = (float*)(ws + 2 * MB);               // 2 KB
    float2*   Cf  = (float2*)(ws + 2 * MB + 0x10000);    // 256 KB
    float*    wts = (float*)(ws + 2 * MB + 0x60000);     // 256 B
    int*      dly = (int*)(ws + 2 * MB + 0x61000);       // 256 B
    // partial [5,21) MiB
    float2*   partial = (float2*)(ws + 5 * MB);
    // Xs [21,85): split X, alive until GEMM2
    ushort_t* Xs  = (ushort_t*)(ws + 21 * MB);
    // [85,149): YT (alive until fft_fwd), then reused as Z (GEMM2 output)
    float*    YT  = (float*)(ws + 85 * MB);
    float*    Z   = YT;

    // 1) weight prep: BsM = split(Wq^T Wk); BsW = split(Wo Wv); bp = Wo bv + bo
    k_prep<<<dim3(32, 32, 2), dim3(16, 16), 0, stream>>>(Wq, Wk, Wo, Wv, BsM, BsW);
    k_biasprep<<<1, 512, 0, stream>>>(Wo, bv, bo, bp);

    // 2) Xs = split(X)
    k_split<<<16384, 256, 0, stream>>>(X, Xs);

    // 3) YT = (X @ M^T)^T   (3-term split MFMA, transposed epilogue)
    k_gemm<3, 0><<<dim3(4, 256), 256, 0, stream>>>(Xs, BsM, nullptr, YT);

    // 4) packed Stockham FFTs (x from X directly, y from YT) + cross-spectrum
    k_fft_fwd<<<512, 256, 0, stream>>>(X, YT, partial);
    k_reduce<<<128, 256, 0, stream>>>(partial, Cf);

    // 5) Z = X @ Wov^T + bp   (plain bf16 MFMA; YT region now dead)
    k_gemm<1, 1><<<dim3(4, 256), 256, 0, stream>>>(Xs, BsW, bp, Z);

    // 6) inverse FFT + top-8 + softmax (fused)
    k_ifft_topk<<<NB, 256, 0, stream>>>(Cf, wts, dly);

    // 7) Out = weighted circular shift-sum of Z
    k_gather<<<16384, 256, 0, stream>>>(Z, wts, dly, Out);
}